// Round 1
// baseline (212.827 us; speedup 1.0000x reference)
//
#include <hip/hip_runtime.h>

// expm of 3.5M symmetric 3x3 matrices, layout (B=4, 9, 96^3) f32.
// Method: scaling (2^-4) + 7-term matrix Taylor (Horner) + 4 squarings.
// All intermediates are polynomials in the same symmetric X -> commute ->
// symmetric, so we carry only 6 unique entries. Branch-free, no eigen
// degeneracy issues.

#define N_VOX (96 * 96 * 96) // 884736, divisible by 4*256

__device__ __forceinline__ void expm3_sym(
    float s00, float s01, float s02, float s11, float s12, float s22,
    float& e00, float& e01, float& e02, float& e11, float& e12, float& e22)
{
    // scale by 2^-4
    const float sc = 0.0625f;
    float x00 = s00 * sc, x01 = s01 * sc, x02 = s02 * sc;
    float x11 = s11 * sc, x12 = s12 * sc, x22 = s22 * sc;

    // Taylor-Horner, m = 7 terms: P = I; for j = 7..1: P = I + (X*P)/j
    float p00 = 1.f, p01 = 0.f, p02 = 0.f, p11 = 1.f, p12 = 0.f, p22 = 1.f;
    const float inv[7] = {1.f, 0.5f, 1.f / 3.f, 0.25f, 0.2f, 1.f / 6.f, 1.f / 7.f};
#pragma unroll
    for (int j = 7; j >= 1; --j) {
        const float invj = inv[j - 1];
        // R = X * P (symmetric since X, P commute)
        float r00 = x00 * p00 + x01 * p01 + x02 * p02;
        float r01 = x00 * p01 + x01 * p11 + x02 * p12;
        float r02 = x00 * p02 + x01 * p12 + x02 * p22;
        float r11 = x01 * p01 + x11 * p11 + x12 * p12;
        float r12 = x01 * p02 + x11 * p12 + x12 * p22;
        float r22 = x02 * p02 + x12 * p12 + x22 * p22;
        p00 = fmaf(r00, invj, 1.f);
        p01 = r01 * invj;
        p02 = r02 * invj;
        p11 = fmaf(r11, invj, 1.f);
        p12 = r12 * invj;
        p22 = fmaf(r22, invj, 1.f);
    }
    // 4 squarings: M <- M*M (symmetric square)
#pragma unroll
    for (int q = 0; q < 4; ++q) {
        float r00 = p00 * p00 + p01 * p01 + p02 * p02;
        float r01 = p00 * p01 + p01 * p11 + p02 * p12;
        float r02 = p00 * p02 + p01 * p12 + p02 * p22;
        float r11 = p01 * p01 + p11 * p11 + p12 * p12;
        float r12 = p01 * p02 + p11 * p12 + p12 * p22;
        float r22 = p02 * p02 + p12 * p12 + p22 * p22;
        p00 = r00; p01 = r01; p02 = r02; p11 = r11; p12 = r12; p22 = r22;
    }
    e00 = p00; e01 = p01; e02 = p02; e11 = p11; e12 = p12; e22 = p22;
}

__global__ __launch_bounds__(256) void Expm_54872502174211_kernel(
    const float* __restrict__ x, float* __restrict__ out)
{
    const size_t n = N_VOX;
    const int b = blockIdx.y;
    const int v4 = blockIdx.x * 256 + threadIdx.x; // group of 4 voxels

    const float* base = x + (size_t)b * 9 * n + (size_t)v4 * 4;
    // channels of the symmetric matrix: 0,1,2,4,5,8 (skip duplicates 3,6,7)
    float4 c0 = *(const float4*)(base + 0 * n);
    float4 c1 = *(const float4*)(base + 1 * n);
    float4 c2 = *(const float4*)(base + 2 * n);
    float4 c4 = *(const float4*)(base + 4 * n);
    float4 c5 = *(const float4*)(base + 5 * n);
    float4 c8 = *(const float4*)(base + 8 * n);

    float4 o0, o1, o2, o4, o5, o8;
    expm3_sym(c0.x, c1.x, c2.x, c4.x, c5.x, c8.x,
              o0.x, o1.x, o2.x, o4.x, o5.x, o8.x);
    expm3_sym(c0.y, c1.y, c2.y, c4.y, c5.y, c8.y,
              o0.y, o1.y, o2.y, o4.y, o5.y, o8.y);
    expm3_sym(c0.z, c1.z, c2.z, c4.z, c5.z, c8.z,
              o0.z, o1.z, o2.z, o4.z, o5.z, o8.z);
    expm3_sym(c0.w, c1.w, c2.w, c4.w, c5.w, c8.w,
              o0.w, o1.w, o2.w, o4.w, o5.w, o8.w);

    float* ob = out + (size_t)b * 9 * n + (size_t)v4 * 4;
    *(float4*)(ob + 0 * n) = o0;
    *(float4*)(ob + 1 * n) = o1;
    *(float4*)(ob + 2 * n) = o2;
    *(float4*)(ob + 3 * n) = o1; // symmetric duplicate of channel 1
    *(float4*)(ob + 4 * n) = o4;
    *(float4*)(ob + 5 * n) = o5;
    *(float4*)(ob + 6 * n) = o2; // dup of 2
    *(float4*)(ob + 7 * n) = o5; // dup of 5
    *(float4*)(ob + 8 * n) = o8;
}

extern "C" void kernel_launch(void* const* d_in, const int* in_sizes, int n_in,
                              void* d_out, int out_size, void* d_ws, size_t ws_size,
                              hipStream_t stream) {
    const float* x = (const float*)d_in[0];
    float* out = (float*)d_out;
    // N_VOX / 4 voxel-groups per batch, 256 threads/block -> 864 blocks; B=4 in y
    dim3 grid(N_VOX / (4 * 256), 4);
    Expm_54872502174211_kernel<<<grid, dim3(256), 0, stream>>>(x, out);
}

// Round 3
// 209.507 us; speedup vs baseline: 1.0159x; 1.0159x over previous
//
#include <hip/hip_runtime.h>

// expm of 3.5M symmetric 3x3 matrices, layout (B=4, 9, 96^3) f32.
// Method: scale 2^-3 + 6-term matrix Taylor (Horner, literal constants only,
// no indexed arrays -> no scratch risk) + 3 squarings. All intermediates are
// polynomials in the same symmetric X -> commute -> symmetric: carry 6 entries.
// Inputs ||S||~<2 -> ||X||<0.25 -> truncation ~1e-8 << 9.6e-2 threshold.

#define N_VOX (96 * 96 * 96) // 884736, divisible by 4*256

typedef float f32x4 __attribute__((ext_vector_type(4))); // clang vector: ok for nontemporal builtins

struct Sym { float a00, a01, a02, a11, a12, a22; };

// R = X * P  (symmetric because X and P=poly(X) commute)
__device__ __forceinline__ Sym smul(const Sym& x, const Sym& p) {
    Sym r;
    r.a00 = fmaf(x.a00, p.a00, fmaf(x.a01, p.a01, x.a02 * p.a02));
    r.a01 = fmaf(x.a00, p.a01, fmaf(x.a01, p.a11, x.a02 * p.a12));
    r.a02 = fmaf(x.a00, p.a02, fmaf(x.a01, p.a12, x.a02 * p.a22));
    r.a11 = fmaf(x.a01, p.a01, fmaf(x.a11, p.a11, x.a12 * p.a12));
    r.a12 = fmaf(x.a01, p.a02, fmaf(x.a11, p.a12, x.a12 * p.a22));
    r.a22 = fmaf(x.a02, p.a02, fmaf(x.a12, p.a12, x.a22 * p.a22));
    return r;
}

// P <- I + R * c   (Horner step)
__device__ __forceinline__ Sym istep(const Sym& r, float c) {
    Sym p;
    p.a00 = fmaf(r.a00, c, 1.f);
    p.a01 = r.a01 * c;
    p.a02 = r.a02 * c;
    p.a11 = fmaf(r.a11, c, 1.f);
    p.a12 = r.a12 * c;
    p.a22 = fmaf(r.a22, c, 1.f);
    return p;
}

__device__ __forceinline__ Sym ssq(const Sym& p) {
    Sym r;
    r.a00 = fmaf(p.a00, p.a00, fmaf(p.a01, p.a01, p.a02 * p.a02));
    r.a01 = fmaf(p.a00, p.a01, fmaf(p.a01, p.a11, p.a02 * p.a12));
    r.a02 = fmaf(p.a00, p.a02, fmaf(p.a01, p.a12, p.a02 * p.a22));
    r.a11 = fmaf(p.a01, p.a01, fmaf(p.a11, p.a11, p.a12 * p.a12));
    r.a12 = fmaf(p.a01, p.a02, fmaf(p.a11, p.a12, p.a12 * p.a22));
    r.a22 = fmaf(p.a02, p.a02, fmaf(p.a12, p.a12, p.a22 * p.a22));
    return r;
}

__device__ __forceinline__ Sym expm3_sym(Sym x) {
    const float sc = 0.125f; // 2^-3
    x.a00 *= sc; x.a01 *= sc; x.a02 *= sc;
    x.a11 *= sc; x.a12 *= sc; x.a22 *= sc;
    // Horner, 6 terms: P = I + X(I + X/2(I + X/3(I + X/4(I + X/5(I + X/6)))))
    Sym p = istep(x, 1.f / 6.f);
    p = istep(smul(x, p), 0.2f);
    p = istep(smul(x, p), 0.25f);
    p = istep(smul(x, p), 1.f / 3.f);
    p = istep(smul(x, p), 0.5f);
    p = istep(smul(x, p), 1.f);
    // 3 squarings (undo 2^-3 scaling)
    p = ssq(p);
    p = ssq(p);
    p = ssq(p);
    return p;
}

__global__ __launch_bounds__(256) void Expm_54872502174211_kernel(
    const float* __restrict__ x, float* __restrict__ out)
{
    const size_t n = N_VOX;
    const int b = blockIdx.y;
    const int v4 = blockIdx.x * 256 + threadIdx.x; // group of 4 voxels

    const float* base = x + (size_t)b * 9 * n + (size_t)v4 * 4;
    // symmetric matrix channels: 0,1,2,4,5,8 (skip duplicates 3,6,7)
    f32x4 c0 = __builtin_nontemporal_load((const f32x4*)(base + 0 * n));
    f32x4 c1 = __builtin_nontemporal_load((const f32x4*)(base + 1 * n));
    f32x4 c2 = __builtin_nontemporal_load((const f32x4*)(base + 2 * n));
    f32x4 c4 = __builtin_nontemporal_load((const f32x4*)(base + 4 * n));
    f32x4 c5 = __builtin_nontemporal_load((const f32x4*)(base + 5 * n));
    f32x4 c8 = __builtin_nontemporal_load((const f32x4*)(base + 8 * n));

    Sym rx = expm3_sym({c0.x, c1.x, c2.x, c4.x, c5.x, c8.x});
    Sym ry = expm3_sym({c0.y, c1.y, c2.y, c4.y, c5.y, c8.y});
    Sym rz = expm3_sym({c0.z, c1.z, c2.z, c4.z, c5.z, c8.z});
    Sym rw = expm3_sym({c0.w, c1.w, c2.w, c4.w, c5.w, c8.w});

    float* ob = out + (size_t)b * 9 * n + (size_t)v4 * 4;
    f32x4 o0 = {rx.a00, ry.a00, rz.a00, rw.a00};
    f32x4 o1 = {rx.a01, ry.a01, rz.a01, rw.a01};
    f32x4 o2 = {rx.a02, ry.a02, rz.a02, rw.a02};
    f32x4 o4 = {rx.a11, ry.a11, rz.a11, rw.a11};
    f32x4 o5 = {rx.a12, ry.a12, rz.a12, rw.a12};
    f32x4 o8 = {rx.a22, ry.a22, rz.a22, rw.a22};
    __builtin_nontemporal_store(o0, (f32x4*)(ob + 0 * n));
    __builtin_nontemporal_store(o1, (f32x4*)(ob + 1 * n));
    __builtin_nontemporal_store(o2, (f32x4*)(ob + 2 * n));
    __builtin_nontemporal_store(o1, (f32x4*)(ob + 3 * n)); // sym dup of 1
    __builtin_nontemporal_store(o4, (f32x4*)(ob + 4 * n));
    __builtin_nontemporal_store(o5, (f32x4*)(ob + 5 * n));
    __builtin_nontemporal_store(o2, (f32x4*)(ob + 6 * n)); // dup of 2
    __builtin_nontemporal_store(o5, (f32x4*)(ob + 7 * n)); // dup of 5
    __builtin_nontemporal_store(o8, (f32x4*)(ob + 8 * n));
}

extern "C" void kernel_launch(void* const* d_in, const int* in_sizes, int n_in,
                              void* d_out, int out_size, void* d_ws, size_t ws_size,
                              hipStream_t stream) {
    const float* x = (const float*)d_in[0];
    float* out = (float*)d_out;
    dim3 grid(N_VOX / (4 * 256), 4); // 864 x 4 blocks, 256 thr, 4 voxels/thr
    Expm_54872502174211_kernel<<<grid, dim3(256), 0, stream>>>(x, out);
}